// Round 5
// baseline (645.746 us; speedup 1.0000x reference)
//
#include <hip/hip_runtime.h>
#include <hip/hip_bf16.h>

// Problem constants: C=8 channels, F=256 features(h), NH=8 heads, W=1024 frames, dh=32.
// out = [8,256,1024] fp32 (2,097,152) then qk = [8,8,1024,1024] fp32 (67,108,864).

typedef float f32x4 __attribute__((ext_vector_type(4)));
typedef short s16x8 __attribute__((ext_vector_type(8)));

static __device__ __forceinline__ unsigned short f2bf(float f) {
  unsigned int u = __builtin_bit_cast(unsigned int, f);
  u += 0x7fff + ((u >> 16) & 1);   // round-to-nearest-even
  return (unsigned short)(u >> 16);
}

// ---------------------------------------------------------------------------
// Kernel 1: convert the 4 positionwise weight tensors [8,256,256] fp32 -> bf16
// ---------------------------------------------------------------------------
__global__ __launch_bounds__(256) void cvt_weights(
    const float* __restrict__ wq, const float* __restrict__ wk,
    const float* __restrict__ wv, const float* __restrict__ wo,
    unsigned short* __restrict__ dst) {
  int gid = blockIdx.x * 256 + threadIdx.x;   // 524288 threads, 4 floats each
  int e = gid * 4;
  int arr = e >> 19;                          // / 524288
  int off = e & 524287;
  const float* src = arr == 0 ? wq : arr == 1 ? wk : arr == 2 ? wv : wo;
  float4 v = *(const float4*)(src + off);
  ushort4 o;
  o.x = f2bf(v.x); o.y = f2bf(v.y); o.z = f2bf(v.z); o.w = f2bf(v.w);
  *(ushort4*)(dst + (size_t)arr * 524288 + off) = o;
}

// ---------------------------------------------------------------------------
// Kernel 2: conv3x3 (pad 1) for q,k,v. x:[8,256,1024] fp32.
// Output transposed bf16: convT[t*8+co][w][h] (h contiguous) = GEMM B layout.
// ---------------------------------------------------------------------------
__global__ __launch_bounds__(256) void conv3x3_k(
    const float* __restrict__ x,
    const float* __restrict__ wq, const float* __restrict__ wk,
    const float* __restrict__ wv,
    unsigned short* __restrict__ convT) {
  __shared__ float xt[8][34][36];
  int t = blockIdx.z;
  const float* wc = (t == 0) ? wq : (t == 1) ? wk : wv;
  int wtile = blockIdx.x * 32, htile = blockIdx.y * 32;
  int tid = threadIdx.x;
  for (int i = tid; i < 8 * 34 * 34; i += 256) {
    int cp = i / 1156;
    int rem = i - cp * 1156;
    int hh = rem / 34, ww = rem - hh * 34;
    int gh = htile + hh - 1, gw = wtile + ww - 1;
    float v = 0.f;
    if ((unsigned)gh < 256u && (unsigned)gw < 1024u)
      v = x[((size_t)cp * 256 + gh) * 1024 + gw];
    xt[cp][hh][ww] = v;
  }
  __syncthreads();
  int tx = tid & 31, strip = tid >> 5;
  int h0 = strip * 4;                      // thread covers 4 consecutive h
  float acc[8][4];
#pragma unroll
  for (int co = 0; co < 8; ++co)
#pragma unroll
    for (int p = 0; p < 4; ++p) acc[co][p] = 0.f;
#pragma unroll 1
  for (int cp = 0; cp < 8; ++cp) {
    float xv[6][3];
#pragma unroll
    for (int rr = 0; rr < 6; ++rr)
#pragma unroll
      for (int cc = 0; cc < 3; ++cc)
        xv[rr][cc] = xt[cp][h0 + rr][tx + cc];
#pragma unroll
    for (int i = 0; i < 3; ++i)
#pragma unroll
      for (int j = 0; j < 3; ++j) {
#pragma unroll
        for (int co = 0; co < 8; ++co) {
          float wgt = wc[((co * 8 + cp) * 3 + i) * 3 + j];  // uniform -> s_load
#pragma unroll
          for (int p = 0; p < 4; ++p)
            acc[co][p] += wgt * xv[p + i][j];
        }
      }
  }
  int w = wtile + tx;
#pragma unroll
  for (int co = 0; co < 8; ++co) {
    ushort4 o;
    o.x = f2bf(acc[co][0]); o.y = f2bf(acc[co][1]);
    o.z = f2bf(acc[co][2]); o.w = f2bf(acc[co][3]);
    *(ushort4*)(convT + ((size_t)(t * 8 + co) * 1024 + w) * 256 + htile + h0) = o;
  }
}

// ---------------------------------------------------------------------------
// Kernel 3/6: batched bf16 MFMA GEMM, M=256(g), N=1024(w), K=256(h).
// ---------------------------------------------------------------------------
__global__ __launch_bounds__(256) void gemm_pw(
    const unsigned short* __restrict__ A0,
    const unsigned short* __restrict__ B0,
    unsigned short* __restrict__ qkh,
    unsigned short* __restrict__ vstd,
    float* __restrict__ outp,
    int mode) {
  int b = blockIdx.z;
  const unsigned short* A = A0 + (size_t)b * 65536;
  const unsigned short* B = B0 + (size_t)b * 262144;
  int lane = threadIdx.x & 63, wvid = threadIdx.x >> 6;
  int wm = wvid & 1, wn = wvid >> 1;
  int mBase = blockIdx.y * 128 + wm * 64;
  int nBase = blockIdx.x * 128 + wn * 64;
  int c15 = lane & 15, klo = (lane >> 4) * 8;
  f32x4 acc[4][4];
#pragma unroll
  for (int mi = 0; mi < 4; ++mi)
#pragma unroll
    for (int ni = 0; ni < 4; ++ni) acc[mi][ni] = (f32x4){0.f, 0.f, 0.f, 0.f};
#pragma unroll 2
  for (int kk = 0; kk < 256; kk += 32) {
    s16x8 af[4], bf[4];
#pragma unroll
    for (int mi = 0; mi < 4; ++mi)
      af[mi] = *(const s16x8*)(A + (size_t)(mBase + mi * 16 + c15) * 256 + kk + klo);
#pragma unroll
    for (int ni = 0; ni < 4; ++ni)
      bf[ni] = *(const s16x8*)(B + (size_t)(nBase + ni * 16 + c15) * 256 + kk + klo);
#pragma unroll
    for (int mi = 0; mi < 4; ++mi)
#pragma unroll
      for (int ni = 0; ni < 4; ++ni)
        acc[mi][ni] = __builtin_amdgcn_mfma_f32_16x16x32_bf16(
            af[mi], bf[ni], acc[mi][ni], 0, 0, 0);
  }
  int r0 = (lane >> 4) * 4;   // C-frag rows = quad*4 + r, cols = lane&15
  if (mode == 0) {
    int t = b >> 3, c = b & 7;
    if (t < 2) {
      unsigned short* dst = qkh + (size_t)t * 2097152 + (size_t)c * 262144;
#pragma unroll
      for (int mi = 0; mi < 4; ++mi)
#pragma unroll
        for (int ni = 0; ni < 4; ++ni) {
          int g = mBase + mi * 16 + r0;
          int w = nBase + ni * 16 + c15;
          int n = g >> 5, d = g & 31;     // d multiple of 4
          ushort4 o;
          o.x = f2bf(acc[mi][ni][0]); o.y = f2bf(acc[mi][ni][1]);
          o.z = f2bf(acc[mi][ni][2]); o.w = f2bf(acc[mi][ni][3]);
          *(ushort4*)(dst + ((size_t)n * 1024 + w) * 32 + d) = o;
        }
    } else {
      unsigned short* dst = vstd + (size_t)c * 262144;
#pragma unroll
      for (int mi = 0; mi < 4; ++mi)
#pragma unroll
        for (int ni = 0; ni < 4; ++ni) {
          int w = nBase + ni * 16 + c15;
#pragma unroll
          for (int r = 0; r < 4; ++r)
            dst[(size_t)(mBase + mi * 16 + r0 + r) * 1024 + w] = f2bf(acc[mi][ni][r]);
        }
    }
  } else {
    float* dst = outp + (size_t)b * 262144;
#pragma unroll
    for (int mi = 0; mi < 4; ++mi)
#pragma unroll
      for (int ni = 0; ni < 4; ++ni) {
        int w = nBase + ni * 16 + c15;
#pragma unroll
        for (int r = 0; r < 4; ++r)
          dst[(size_t)(mBase + mi * 16 + r0 + r) * 1024 + w] = acc[mi][ni][r];
      }
  }
}

// ---------------------------------------------------------------------------
// Kernel 3.5: zero the partial-O / partial-lsum buffers (8.25 MB).
// ---------------------------------------------------------------------------
__global__ __launch_bounds__(256) void zero_ws(float4* __restrict__ dst) {
  dst[(size_t)blockIdx.x * 256 + threadIdx.x] =
      make_float4(0.f, 0.f, 0.f, 0.f);
}

// ---------------------------------------------------------------------------
// Kernel 4: flash attention per (c,n) pair + 64-row q block + k-HALF.
// Q,K: [cn][pos][32] bf16. V: [c][h][w] bf16. prev/qk: [cn][q][k] fp32.
// 4 waves; each wave privately owns 16 q rows. NO max-tracking (|qk| <~ 8).
//
// v6: K-SPLIT x2. Evidence from v2-v5: delivered BW ~= 0.08 TB/s per
// occupancy-%, invariant to address pattern (64B/256B/1KB bursts) and to
// source-level prefetch (compiler sinks it, v5 VGPR=48) -> each wave is
// serialized at ~1 outstanding VMEM op; BW scales with RESIDENT WAVES.
// Occupancy was grid-limited: 1024 blocks x 4 waves = 4096 waves = 50% of
// the 8192 slots. Splitting the k-range across blockIdx.z in {0,1} doubles
// the grid to 8192 waves (100% ceiling). Each half accumulates unnormalized
// O and row-sums; halves are combined via fp32 atomicAdd into zeroed
// workspace (exactly 2 adders/address -> deterministic), then combine_k
// normalizes. Kernel body is byte-identical to v2 (the 178.8us structure,
// plain qk stores - NT hurt in v5). No __syncthreads: P LDS wave-private.
// ---------------------------------------------------------------------------
__global__ __launch_bounds__(256, 8) void attn_k(
    const unsigned short* __restrict__ Qh,
    const unsigned short* __restrict__ Kh,
    const unsigned short* __restrict__ Vstd,
    const float* __restrict__ prev,
    float* __restrict__ qkOut,
    float* __restrict__ Opart,
    float* __restrict__ lpart) {
  __shared__ unsigned short plds[4][16 * 72];   // 144B row stride, wave-private
  int lane = threadIdx.x & 63, wvid = threadIdx.x >> 6;
  int cn = blockIdx.y;
  int c = cn >> 3, n = cn & 7;
  int qBase = blockIdx.x * 64 + wvid * 16;
  int kb0 = blockIdx.z << 9;                    // k-half base: 0 or 512
  int c15 = lane & 15, quad = lane >> 4, klo = quad * 8;
  const unsigned short* Q = Qh + (size_t)cn * 32768;
  const unsigned short* K = Kh + (size_t)cn * 32768;
  const unsigned short* V = Vstd + (size_t)c * 262144 + (size_t)n * 32768;
  // per-lane base: q row = qBase + c15, fine k offset = quad*4 (dwordx4)
  const float* prevB = prev + (size_t)cn * 1048576 + (size_t)(qBase + c15) * 1024 + quad * 4;
  float* qkB = qkOut + (size_t)cn * 1048576 + (size_t)(qBase + c15) * 1024 + quad * 4;
  s16x8 qf = *(const s16x8*)(Q + (size_t)(qBase + c15) * 32 + klo);
  f32x4 o0 = {0.f, 0.f, 0.f, 0.f}, o1 = {0.f, 0.f, 0.f, 0.f};
  float lsum = 0.f;
  unsigned short* pw = plds[wvid];

  // prefetch chunk 0 of this half (K fragments + prev tile)
  f32x4 pvA[4];
  s16x8 kfA[4];
#pragma unroll
  for (int kt = 0; kt < 4; ++kt) {
    kfA[kt] = *(const s16x8*)(K + (size_t)(kb0 + kt * 16 + c15) * 32 + klo);
    pvA[kt] = *(const f32x4*)(prevB + kb0 + kt * 16);
  }

#pragma unroll 1
  for (int ko = 0; ko < 512; ko += 64) {
    int kb = kb0 + ko;
    int kbn = kb0 + ((ko + 64) & 511);   // wraps within the half on last iter
    // S^T = K Q^T (uses prefetched K frags): lane holds k=quad*4+r, q=c15
    f32x4 s2[4];
#pragma unroll
    for (int kt = 0; kt < 4; ++kt) {
      f32x4 z = {0.f, 0.f, 0.f, 0.f};
      s2[kt] = __builtin_amdgcn_mfma_f32_16x16x32_bf16(kfA[kt], qf, z, 0, 0, 0);
    }
    // this-chunk V fragments (issued BEFORE the store burst)
    s16x8 vf[2][2];
#pragma unroll
    for (int kk2 = 0; kk2 < 2; ++kk2) {
      vf[kk2][0] = *(const s16x8*)(V + (size_t)c15 * 1024 + kb + kk2 * 32 + klo);
      vf[kk2][1] = *(const s16x8*)(V + (size_t)(16 + c15) * 1024 + kb + kk2 * 32 + klo);
    }
    // next-chunk prefetch (also before the store burst)
    f32x4 pvN[4];
    s16x8 kfN[4];
#pragma unroll
    for (int kt = 0; kt < 4; ++kt) {
      kfN[kt] = *(const s16x8*)(K + (size_t)(kbn + kt * 16 + c15) * 32 + klo);
      pvN[kt] = *(const f32x4*)(prevB + kbn + kt * 16);
    }
    // scale, add prev, emit qk (plain dwordx4), exp, row-sum, stage P
#pragma unroll
    for (int kt = 0; kt < 4; ++kt) {
      f32x4 val = s2[kt] * 0.0625f + pvA[kt];
      *(f32x4*)(qkB + kb + kt * 16) = val;
      float p0 = __expf(val[0]), p1 = __expf(val[1]),
            p2 = __expf(val[2]), p3 = __expf(val[3]);
      lsum += (p0 + p1) + (p2 + p3);
      ushort4 pk;
      pk.x = f2bf(p0); pk.y = f2bf(p1); pk.z = f2bf(p2); pk.w = f2bf(p3);
      *(ushort4*)(pw + c15 * 72 + kt * 16 + quad * 4) = pk;   // P[q=c15][k]
    }
    // PV: O[q][d] += P[q][k] V[k][d]  (V frags already in registers)
#pragma unroll
    for (int kk2 = 0; kk2 < 2; ++kk2) {
      s16x8 pf = *(const s16x8*)(pw + c15 * 72 + kk2 * 32 + klo);
      o0 = __builtin_amdgcn_mfma_f32_16x16x32_bf16(pf, vf[kk2][0], o0, 0, 0, 0);
      o1 = __builtin_amdgcn_mfma_f32_16x16x32_bf16(pf, vf[kk2][1], o1, 0, 0, 0);
    }
    // rotate prefetch buffers
#pragma unroll
    for (int kt = 0; kt < 4; ++kt) {
      kfA[kt] = kfN[kt];
      pvA[kt] = pvN[kt];
    }
  }
  // reduce row-sums across the 4 quads holding the same q row
  lsum += __shfl_xor(lsum, 16);
  lsum += __shfl_xor(lsum, 32);
  // epilogue: accumulate this half's unnormalized O and row-sums.
  // Opart layout [cn][d=32][q=1024] fp32 -> combine_k reads/writes coalesced.
  float* OpartB = Opart + (size_t)cn * 32768;
  if (quad == 0) atomicAdd(lpart + cn * 1024 + qBase + c15, lsum);
#pragma unroll
  for (int r = 0; r < 4; ++r) {
    int q = qBase + quad * 4 + r;        // O-frag: q = quad*4 + r, d = c15
    atomicAdd(OpartB + (size_t)c15 * 1024 + q, o0[r]);
    atomicAdd(OpartB + (size_t)(16 + c15) * 1024 + q, o1[r]);
  }
}

// ---------------------------------------------------------------------------
// Kernel 4.5: combine k-halves -> a[c][h][w] fp32 (normalize by row-sum)
// ---------------------------------------------------------------------------
__global__ __launch_bounds__(256) void combine_k(
    const float* __restrict__ Opart, const float* __restrict__ lpart,
    float* __restrict__ aOut) {
  int cn = blockIdx.y;
  int c = cn >> 3, n = cn & 7;
  int lane = threadIdx.x & 63;
  int q = blockIdx.x * 64 + lane;
  int dg = threadIdx.x >> 6;           // 4 waves, 8 d-values each
  float inv = 1.0f / lpart[cn * 1024 + q];
#pragma unroll
  for (int dd = 0; dd < 8; ++dd) {
    int d = dg * 8 + dd;
    aOut[((size_t)(c * 256) + n * 32 + d) * 1024 + q] =
        Opart[((size_t)cn * 32 + d) * 1024 + q] * inv;
  }
}

// ---------------------------------------------------------------------------
// Kernel 5: o = wo_dw @ a (8x8 channel mix) + transpose -> ot[c][w][h] bf16
// ---------------------------------------------------------------------------
__global__ __launch_bounds__(256) void mix_t(
    const float* __restrict__ a, const float* __restrict__ dw,
    unsigned short* __restrict__ ot) {
  int tx = threadIdx.x & 31, strip = threadIdx.x >> 5;
  int wtile = blockIdx.x * 32, htile = blockIdx.y * 32;
  int w = wtile + tx, h0 = htile + strip * 4;
  float acc[8][4];
#pragma unroll
  for (int co = 0; co < 8; ++co)
#pragma unroll
    for (int p = 0; p < 4; ++p) acc[co][p] = 0.f;
#pragma unroll 1
  for (int cp = 0; cp < 8; ++cp) {
    float av[4];
#pragma unroll
    for (int p = 0; p < 4; ++p)
      av[p] = a[((size_t)cp * 256 + h0 + p) * 1024 + w];
#pragma unroll
    for (int co = 0; co < 8; ++co) {
      float wgt = dw[co * 8 + cp];   // uniform -> scalar
#pragma unroll
      for (int p = 0; p < 4; ++p) acc[co][p] += wgt * av[p];
    }
  }
#pragma unroll
  for (int co = 0; co < 8; ++co) {
    ushort4 o;
    o.x = f2bf(acc[co][0]); o.y = f2bf(acc[co][1]);
    o.z = f2bf(acc[co][2]); o.w = f2bf(acc[co][3]);
    *(ushort4*)(ot + ((size_t)co * 1024 + w) * 256 + h0) = o;
  }
}

// ---------------------------------------------------------------------------
extern "C" void kernel_launch(void* const* d_in, const int* in_sizes, int n_in,
                              void* d_out, int out_size, void* d_ws, size_t ws_size,
                              hipStream_t stream) {
  (void)in_sizes; (void)n_in; (void)out_size; (void)ws_size;
  const float* x       = (const float*)d_in[0];
  const float* prev    = (const float*)d_in[1];
  const float* wq_conv = (const float*)d_in[2];
  const float* wk_conv = (const float*)d_in[3];
  const float* wv_conv = (const float*)d_in[4];
  const float* wq_pw   = (const float*)d_in[5];
  const float* wk_pw   = (const float*)d_in[6];
  const float* wv_pw   = (const float*)d_in[7];
  const float* wo_dw   = (const float*)d_in[8];
  const float* wo_pw   = (const float*)d_in[9];

  float* outp  = (float*)d_out;             // [8][256][1024]
  float* qkOut = outp + 2097152;            // [64][1024][1024]

  // workspace layout (40 MB total)
  // [0,4)   pwB: 4 x 524288 bf16 (wo slice at [3,4) live till the end)
  // [4,16)  convT: 24 x 262144 bf16 — DEAD after gemm mode 0; hole reused:
  //         [4,12)     Opart: 64 x 32 x 1024 fp32 (8 MB)
  //         [12,12.25) lpart: 64 x 1024 fp32 (256 KB)
  // [16,24) qkh  [24,28) vstd  [28,36) aBuf  [36,40) otB
  char* ws = (char*)d_ws;
  unsigned short* pwB   = (unsigned short*)ws;
  unsigned short* convT = (unsigned short*)(ws + (4  << 20));
  float*          Opart = (float*)         (ws + (4  << 20));
  float*          lpart = (float*)         (ws + (12 << 20));
  unsigned short* qkh   = (unsigned short*)(ws + (16 << 20));
  unsigned short* vstd  = (unsigned short*)(ws + (24 << 20));
  float*          aBuf  = (float*)         (ws + (28 << 20));
  unsigned short* otB   = (unsigned short*)(ws + (36 << 20));

  cvt_weights<<<2048, 256, 0, stream>>>(wq_pw, wk_pw, wv_pw, wo_pw, pwB);
  conv3x3_k<<<dim3(32, 8, 3), 256, 0, stream>>>(x, wq_conv, wk_conv, wv_conv, convT);
  gemm_pw<<<dim3(8, 2, 24), 256, 0, stream>>>(pwB, convT, qkh, vstd, nullptr, 0);
  // zero Opart+lpart (8.25 MB = 540672 float4s = 2112 blocks x 256 threads)
  zero_ws<<<2112, 256, 0, stream>>>((float4*)Opart);
  attn_k<<<dim3(16, 64, 2), 256, 0, stream>>>(qkh, qkh + 2097152, vstd, prev,
                                              qkOut, Opart, lpart);
  combine_k<<<dim3(16, 64), 256, 0, stream>>>(Opart, lpart, aBuf);
  mix_t<<<dim3(32, 8), 256, 0, stream>>>(aBuf, wo_dw, otB);
  gemm_pw<<<dim3(8, 2, 8), 256, 0, stream>>>(pwB + 3 * 524288, otB, nullptr, nullptr, outp, 1);
}

// Round 7
// 539.681 us; speedup vs baseline: 1.1965x; 1.1965x over previous
//
#include <hip/hip_runtime.h>
#include <hip/hip_bf16.h>

// Problem constants: C=8 channels, F=256 features(h), NH=8 heads, W=1024 frames, dh=32.
// out = [8,256,1024] fp32 (2,097,152) then qk = [8,8,1024,1024] fp32 (67,108,864).

typedef float f32x4 __attribute__((ext_vector_type(4)));
typedef short s16x8 __attribute__((ext_vector_type(8)));

static __device__ __forceinline__ unsigned short f2bf(float f) {
  unsigned int u = __builtin_bit_cast(unsigned int, f);
  u += 0x7fff + ((u >> 16) & 1);   // round-to-nearest-even
  return (unsigned short)(u >> 16);
}

// ---------------------------------------------------------------------------
// Kernel 1: convert the 4 positionwise weight tensors [8,256,256] fp32 -> bf16
// ---------------------------------------------------------------------------
__global__ __launch_bounds__(256) void cvt_weights(
    const float* __restrict__ wq, const float* __restrict__ wk,
    const float* __restrict__ wv, const float* __restrict__ wo,
    unsigned short* __restrict__ dst) {
  int gid = blockIdx.x * 256 + threadIdx.x;   // 524288 threads, 4 floats each
  int e = gid * 4;
  int arr = e >> 19;                          // / 524288
  int off = e & 524287;
  const float* src = arr == 0 ? wq : arr == 1 ? wk : arr == 2 ? wv : wo;
  float4 v = *(const float4*)(src + off);
  ushort4 o;
  o.x = f2bf(v.x); o.y = f2bf(v.y); o.z = f2bf(v.z); o.w = f2bf(v.w);
  *(ushort4*)(dst + (size_t)arr * 524288 + off) = o;
}

// ---------------------------------------------------------------------------
// Kernel 2: conv3x3 (pad 1) for q,k,v. x:[8,256,1024] fp32.
// Output transposed bf16: convT[t*8+co][w][h] (h contiguous) = GEMM B layout.
// ---------------------------------------------------------------------------
__global__ __launch_bounds__(256) void conv3x3_k(
    const float* __restrict__ x,
    const float* __restrict__ wq, const float* __restrict__ wk,
    const float* __restrict__ wv,
    unsigned short* __restrict__ convT) {
  __shared__ float xt[8][34][36];
  int t = blockIdx.z;
  const float* wc = (t == 0) ? wq : (t == 1) ? wk : wv;
  int wtile = blockIdx.x * 32, htile = blockIdx.y * 32;
  int tid = threadIdx.x;
  for (int i = tid; i < 8 * 34 * 34; i += 256) {
    int cp = i / 1156;
    int rem = i - cp * 1156;
    int hh = rem / 34, ww = rem - hh * 34;
    int gh = htile + hh - 1, gw = wtile + ww - 1;
    float v = 0.f;
    if ((unsigned)gh < 256u && (unsigned)gw < 1024u)
      v = x[((size_t)cp * 256 + gh) * 1024 + gw];
    xt[cp][hh][ww] = v;
  }
  __syncthreads();
  int tx = tid & 31, strip = tid >> 5;
  int h0 = strip * 4;                      // thread covers 4 consecutive h
  float acc[8][4];
#pragma unroll
  for (int co = 0; co < 8; ++co)
#pragma unroll
    for (int p = 0; p < 4; ++p) acc[co][p] = 0.f;
#pragma unroll 1
  for (int cp = 0; cp < 8; ++cp) {
    float xv[6][3];
#pragma unroll
    for (int rr = 0; rr < 6; ++rr)
#pragma unroll
      for (int cc = 0; cc < 3; ++cc)
        xv[rr][cc] = xt[cp][h0 + rr][tx + cc];
#pragma unroll
    for (int i = 0; i < 3; ++i)
#pragma unroll
      for (int j = 0; j < 3; ++j) {
#pragma unroll
        for (int co = 0; co < 8; ++co) {
          float wgt = wc[((co * 8 + cp) * 3 + i) * 3 + j];  // uniform -> s_load
#pragma unroll
          for (int p = 0; p < 4; ++p)
            acc[co][p] += wgt * xv[p + i][j];
        }
      }
  }
  int w = wtile + tx;
#pragma unroll
  for (int co = 0; co < 8; ++co) {
    ushort4 o;
    o.x = f2bf(acc[co][0]); o.y = f2bf(acc[co][1]);
    o.z = f2bf(acc[co][2]); o.w = f2bf(acc[co][3]);
    *(ushort4*)(convT + ((size_t)(t * 8 + co) * 1024 + w) * 256 + htile + h0) = o;
  }
}

// ---------------------------------------------------------------------------
// Kernel 3/6: batched bf16 MFMA GEMM, M=256(g), N=1024(w), K=256(h).
// ---------------------------------------------------------------------------
__global__ __launch_bounds__(256) void gemm_pw(
    const unsigned short* __restrict__ A0,
    const unsigned short* __restrict__ B0,
    unsigned short* __restrict__ qkh,
    unsigned short* __restrict__ vstd,
    float* __restrict__ outp,
    int mode) {
  int b = blockIdx.z;
  const unsigned short* A = A0 + (size_t)b * 65536;
  const unsigned short* B = B0 + (size_t)b * 262144;
  int lane = threadIdx.x & 63, wvid = threadIdx.x >> 6;
  int wm = wvid & 1, wn = wvid >> 1;
  int mBase = blockIdx.y * 128 + wm * 64;
  int nBase = blockIdx.x * 128 + wn * 64;
  int c15 = lane & 15, klo = (lane >> 4) * 8;
  f32x4 acc[4][4];
#pragma unroll
  for (int mi = 0; mi < 4; ++mi)
#pragma unroll
    for (int ni = 0; ni < 4; ++ni) acc[mi][ni] = (f32x4){0.f, 0.f, 0.f, 0.f};
#pragma unroll 2
  for (int kk = 0; kk < 256; kk += 32) {
    s16x8 af[4], bf[4];
#pragma unroll
    for (int mi = 0; mi < 4; ++mi)
      af[mi] = *(const s16x8*)(A + (size_t)(mBase + mi * 16 + c15) * 256 + kk + klo);
#pragma unroll
    for (int ni = 0; ni < 4; ++ni)
      bf[ni] = *(const s16x8*)(B + (size_t)(nBase + ni * 16 + c15) * 256 + kk + klo);
#pragma unroll
    for (int mi = 0; mi < 4; ++mi)
#pragma unroll
      for (int ni = 0; ni < 4; ++ni)
        acc[mi][ni] = __builtin_amdgcn_mfma_f32_16x16x32_bf16(
            af[mi], bf[ni], acc[mi][ni], 0, 0, 0);
  }
  int r0 = (lane >> 4) * 4;   // C-frag rows = quad*4 + r, cols = lane&15
  if (mode == 0) {
    int t = b >> 3, c = b & 7;
    if (t < 2) {
      unsigned short* dst = qkh + (size_t)t * 2097152 + (size_t)c * 262144;
#pragma unroll
      for (int mi = 0; mi < 4; ++mi)
#pragma unroll
        for (int ni = 0; ni < 4; ++ni) {
          int g = mBase + mi * 16 + r0;
          int w = nBase + ni * 16 + c15;
          int n = g >> 5, d = g & 31;     // d multiple of 4
          ushort4 o;
          o.x = f2bf(acc[mi][ni][0]); o.y = f2bf(acc[mi][ni][1]);
          o.z = f2bf(acc[mi][ni][2]); o.w = f2bf(acc[mi][ni][3]);
          *(ushort4*)(dst + ((size_t)n * 1024 + w) * 32 + d) = o;
        }
    } else {
      unsigned short* dst = vstd + (size_t)c * 262144;
#pragma unroll
      for (int mi = 0; mi < 4; ++mi)
#pragma unroll
        for (int ni = 0; ni < 4; ++ni) {
          int w = nBase + ni * 16 + c15;
#pragma unroll
          for (int r = 0; r < 4; ++r)
            dst[(size_t)(mBase + mi * 16 + r0 + r) * 1024 + w] = f2bf(acc[mi][ni][r]);
        }
    }
  } else {
    float* dst = outp + (size_t)b * 262144;
#pragma unroll
    for (int mi = 0; mi < 4; ++mi)
#pragma unroll
      for (int ni = 0; ni < 4; ++ni) {
        int w = nBase + ni * 16 + c15;
#pragma unroll
        for (int r = 0; r < 4; ++r)
          dst[(size_t)(mBase + mi * 16 + r0 + r) * 1024 + w] = acc[mi][ni][r];
      }
  }
}

// ---------------------------------------------------------------------------
// Kernel 4: flash attention, one block per (cn, 16 q-rows). NO k-loop.
// Q,K: [cn][pos][32] bf16. V: [c][h][w] bf16. prev/qk: [cn][q][k] fp32.
//
// v7b: SINGLE-VISIT MONOTONIC STREAMING (resubmit of v7 after infra failure;
// only change: __align__(16) on the LDS buffer so f32x4/s16x8 LDS accesses
// are guaranteed 16B-aligned).
// Evidence: BW saturates at ~2.7 TB/s independent of occupancy (33% vs 66%,
// round 5) and of burst size (64B/256B/1KB, rounds 1-3), while the harness
// fill streams 6.4 TB/s at 10% occupancy -> the ceiling is the device-level
// stream pattern (16k concurrent fine-grained row-streams, each 4KB row
// visited 4-16 times), not wave MLP. Now each 4KB qk/prev row is touched
// EXACTLY ONCE, start to finish:
//   Phase 1: full 16q x 1024k S^T tile in 64KB LDS (4 waves, k-split 256,
//            16 MFMA each; granule-XOR swizzle g^=(q&7) for banking).
//   Phase 2: wave w streams rows 4w..4w+3 monotonically: per row ONE
//            contiguous 4KB prev read + 4KB qk write (4x f32x4/lane),
//            exp -> P bf16 overwrites consumed S in place (swizzled).
//            Block extent = contiguous 64KB read + 64KB write, like a copy.
//   Phase 3: PV per wave over its k-range; in-block O/lsum reduction
//            (no atomics, no zero/combine kernels).
// 4 barriers, LDS 64KB -> 2 blocks/CU; fill proves contiguous streams don't
// need occupancy. NO max-tracking (|qk| <~ 8, exp cannot overflow).
// ---------------------------------------------------------------------------
__global__ __launch_bounds__(256, 2) void attn_k(
    const unsigned short* __restrict__ Qh,
    const unsigned short* __restrict__ Kh,
    const unsigned short* __restrict__ Vstd,
    const float* __restrict__ prev,
    float* __restrict__ qkOut,
    float* __restrict__ aOut) {
  __shared__ __align__(16) float sT[16384];  // 64KB: 16 rows x 1024 fp32
  int lane = threadIdx.x & 63, w = threadIdx.x >> 6;
  int cn = blockIdx.y;
  int c = cn >> 3, n = cn & 7;
  int qBase = blockIdx.x * 16;
  int c15 = lane & 15, quad = lane >> 4, klo = quad * 8;
  const unsigned short* Q = Qh + (size_t)cn * 32768;
  const unsigned short* K = Kh + (size_t)cn * 32768;
  const unsigned short* V = Vstd + (size_t)c * 262144 + (size_t)n * 32768;
  const float* prevB = prev + (size_t)cn * 1048576 + (size_t)qBase * 1024;
  float* qkB = qkOut + (size_t)cn * 1048576 + (size_t)qBase * 1024;

  s16x8 qf = *(const s16x8*)(Q + (size_t)(qBase + c15) * 32 + klo);

  // ---- Phase 1: S^T = K Q^T, wave w covers k in [256w, 256w+256) ----
  // MFMA frag: lane holds (k = 256w + kt*16 + quad*4 + r, q = c15).
  // 16B granule index g = 64w + kt*4 + quad, stored at g ^ (q&7).
#pragma unroll
  for (int kt = 0; kt < 16; ++kt) {
    s16x8 kf = *(const s16x8*)(K + (size_t)(w * 256 + kt * 16 + c15) * 32 + klo);
    f32x4 z = {0.f, 0.f, 0.f, 0.f};
    f32x4 s2 = __builtin_amdgcn_mfma_f32_16x16x32_bf16(kf, qf, z, 0, 0, 0);
    *(f32x4*)(sT + c15 * 1024 + (((w * 64 + kt * 4 + quad) ^ (c15 & 7)) << 2)) = s2;
  }
  __syncthreads();

  // ---- Phase 2: wave w streams rows 4w..4w+3, each row ONE monotonic pass ----
  float lsums[4] = {0.f, 0.f, 0.f, 0.f};
  {
    int q0 = 4 * w;
    f32x4 pv[4], pvN[4];
#pragma unroll
    for (int p = 0; p < 4; ++p)
      pv[p] = *(const f32x4*)(prevB + (size_t)q0 * 1024 + p * 256 + lane * 4);
#pragma unroll
    for (int jr = 0; jr < 4; ++jr) {
      int q = q0 + jr;
      if (jr < 3) {
#pragma unroll
        for (int p = 0; p < 4; ++p)
          pvN[p] = *(const f32x4*)(prevB + (size_t)(q + 1) * 1024 + p * 256 + lane * 4);
      }
#pragma unroll
      for (int p = 0; p < 4; ++p) {
        // S read: granule g = p*64 + lane within row q (swizzled)
        f32x4 sv = *(const f32x4*)(sT + q * 1024 + (((p * 64 + lane) ^ (q & 7)) << 2));
        f32x4 val = sv * 0.0625f + pv[p];
        *(f32x4*)(qkB + (size_t)q * 1024 + p * 256 + lane * 4) = val;
        float e0 = __expf(val[0]), e1 = __expf(val[1]),
              e2 = __expf(val[2]), e3 = __expf(val[3]);
        lsums[jr] += (e0 + e1) + (e2 + e3);
        ushort4 pk;
        pk.x = f2bf(e0); pk.y = f2bf(e1); pk.z = f2bf(e2); pk.w = f2bf(e3);
        // P row q (2KB bf16) overwrites first 2KB of S row q, granules
        // gp = p*32 + (lane>>1) (16B, swizzled ^(q&7)), 8B half = lane&1.
        // Safe: P granules [32p,32p+32) lie in S granules consumed at piece
        // <= p (same-wave program order).
        *(ushort4*)((char*)sT + q * 4096 +
                    (((p * 32 + (lane >> 1)) ^ (q & 7)) << 4) + ((lane & 1) << 3)) = pk;
      }
#pragma unroll
      for (int p = 0; p < 4; ++p) pv[p] = pvN[p];
    }
  }
  __syncthreads();

  // ---- Phase 3: PV, wave w covers k in [256w, 256w+256) ----
  f32x4 o0 = {0.f, 0.f, 0.f, 0.f}, o1 = {0.f, 0.f, 0.f, 0.f};
#pragma unroll
  for (int j = 0; j < 8; ++j) {
    // P frag: q=c15, k = 256w + j*32 + quad*8 -> granule gp = 32w + j*4 + quad
    s16x8 pf = *(const s16x8*)((char*)sT + c15 * 4096 +
                               (((w * 32 + j * 4 + quad) ^ (c15 & 7)) << 4));
    s16x8 v0 = *(const s16x8*)(V + (size_t)c15 * 1024 + w * 256 + j * 32 + klo);
    s16x8 v1 = *(const s16x8*)(V + (size_t)(16 + c15) * 1024 + w * 256 + j * 32 + klo);
    o0 = __builtin_amdgcn_mfma_f32_16x16x32_bf16(pf, v0, o0, 0, 0, 0);
    o1 = __builtin_amdgcn_mfma_f32_16x16x32_bf16(pf, v1, o1, 0, 0, 0);
  }
  // full row sums: rows 4w..4w+3 are wholly owned by this wave
#pragma unroll
  for (int jr = 0; jr < 4; ++jr) {
    float t = lsums[jr];
    t += __shfl_xor(t, 1);  t += __shfl_xor(t, 2);
    t += __shfl_xor(t, 4);  t += __shfl_xor(t, 8);
    t += __shfl_xor(t, 16); t += __shfl_xor(t, 32);
    lsums[jr] = t;
  }
  __syncthreads();   // all PV reads done; S/P area reusable
  // ---- epilogue: cross-wave O reduce in LDS, normalize, write aOut ----
  float* opart = sT;             // [w][d=32][q=16] fp32 = 8KB
  float* lsumArr = sT + 2048;    // [16]
  *(f32x4*)(opart + w * 512 + c15 * 16 + quad * 4) = o0;          // q=quad*4+r
  *(f32x4*)(opart + w * 512 + (16 + c15) * 16 + quad * 4) = o1;
  if (lane == 0) {
    lsumArr[4 * w + 0] = lsums[0];
    lsumArr[4 * w + 1] = lsums[1];
    lsumArr[4 * w + 2] = lsums[2];
    lsumArr[4 * w + 3] = lsums[3];
  }
  __syncthreads();
  int q = threadIdx.x & 15, d = threadIdx.x >> 4;   // d in [0,16)
  float inv = 1.0f / lsumArr[q];
  float s0 = opart[d * 16 + q] + opart[512 + d * 16 + q] +
             opart[1024 + d * 16 + q] + opart[1536 + d * 16 + q];
  int d1 = d + 16;
  float s1 = opart[d1 * 16 + q] + opart[512 + d1 * 16 + q] +
             opart[1024 + d1 * 16 + q] + opart[1536 + d1 * 16 + q];
  aOut[((size_t)(c * 256 + n * 32 + d)) * 1024 + qBase + q] = s0 * inv;
  aOut[((size_t)(c * 256 + n * 32 + d1)) * 1024 + qBase + q] = s1 * inv;
}

// ---------------------------------------------------------------------------
// Kernel 5: o = wo_dw @ a (8x8 channel mix) + transpose -> ot[c][w][h] bf16
// ---------------------------------------------------------------------------
__global__ __launch_bounds__(256) void mix_t(
    const float* __restrict__ a, const float* __restrict__ dw,
    unsigned short* __restrict__ ot) {
  int tx = threadIdx.x & 31, strip = threadIdx.x >> 5;
  int wtile = blockIdx.x * 32, htile = blockIdx.y * 32;
  int w = wtile + tx, h0 = htile + strip * 4;
  float acc[8][4];
#pragma unroll
  for (int co = 0; co < 8; ++co)
#pragma unroll
    for (int p = 0; p < 4; ++p) acc[co][p] = 0.f;
#pragma unroll 1
  for (int cp = 0; cp < 8; ++cp) {
    float av[4];
#pragma unroll
    for (int p = 0; p < 4; ++p)
      av[p] = a[((size_t)cp * 256 + h0 + p) * 1024 + w];
#pragma unroll
    for (int co = 0; co < 8; ++co) {
      float wgt = dw[co * 8 + cp];   // uniform -> scalar
#pragma unroll
      for (int p = 0; p < 4; ++p) acc[co][p] += wgt * av[p];
    }
  }
#pragma unroll
  for (int co = 0; co < 8; ++co) {
    ushort4 o;
    o.x = f2bf(acc[co][0]); o.y = f2bf(acc[co][1]);
    o.z = f2bf(acc[co][2]); o.w = f2bf(acc[co][3]);
    *(ushort4*)(ot + ((size_t)co * 1024 + w) * 256 + h0) = o;
  }
}

// ---------------------------------------------------------------------------
extern "C" void kernel_launch(void* const* d_in, const int* in_sizes, int n_in,
                              void* d_out, int out_size, void* d_ws, size_t ws_size,
                              hipStream_t stream) {
  (void)in_sizes; (void)n_in; (void)out_size; (void)ws_size;
  const float* x       = (const float*)d_in[0];
  const float* prev    = (const float*)d_in[1];
  const float* wq_conv = (const float*)d_in[2];
  const float* wk_conv = (const float*)d_in[3];
  const float* wv_conv = (const float*)d_in[4];
  const float* wq_pw   = (const float*)d_in[5];
  const float* wk_pw   = (const float*)d_in[6];
  const float* wv_pw   = (const float*)d_in[7];
  const float* wo_dw   = (const float*)d_in[8];
  const float* wo_pw   = (const float*)d_in[9];

  float* outp  = (float*)d_out;             // [8][256][1024]
  float* qkOut = outp + 2097152;            // [64][1024][1024]

  // workspace layout (40 MB total)
  char* ws = (char*)d_ws;
  unsigned short* pwB   = (unsigned short*)ws;                // 4 x 524288 bf16 (4 MB)
  unsigned short* convT = (unsigned short*)(ws + (4  << 20)); // 24 x 262144 bf16 (12 MB)
  unsigned short* qkh   = (unsigned short*)(ws + (16 << 20)); // Q,K: 2 x 2097152 bf16 (8 MB)
  unsigned short* vstd  = (unsigned short*)(ws + (24 << 20)); // V: 2097152 bf16 (4 MB)
  float*          aBuf  = (float*)         (ws + (28 << 20)); // a: 2097152 fp32 (8 MB)
  unsigned short* otB   = (unsigned short*)(ws + (36 << 20)); // ot: 2097152 bf16 (4 MB)

  cvt_weights<<<2048, 256, 0, stream>>>(wq_pw, wk_pw, wv_pw, wo_pw, pwB);
  conv3x3_k<<<dim3(32, 8, 3), 256, 0, stream>>>(x, wq_conv, wk_conv, wv_conv, convT);
  gemm_pw<<<dim3(8, 2, 24), 256, 0, stream>>>(pwB, convT, qkh, vstd, nullptr, 0);
  attn_k<<<dim3(64, 64), 256, 0, stream>>>(qkh, qkh + 2097152, vstd, prev, qkOut, aBuf);
  mix_t<<<dim3(32, 8), 256, 0, stream>>>(aBuf, wo_dw, otB);
  gemm_pw<<<dim3(8, 2, 8), 256, 0, stream>>>(pwB + 3 * 524288, otB, nullptr, nullptr, outp, 1);
}